// Round 3
// 75.749 us; speedup vs baseline: 1.1879x; 1.1879x over previous
//
#include <hip/hip_runtime.h>

// Soft histogram via quantization table:
//   hist[b,c,j] = (1/P) * sum_pixels f_j(x),  f_j(x) = k_j(x)/(sum_j k_j(x)+1e-12)
// f depends only on x -> quantize x into NQ cells, precompute f at cell centers,
// reduce to integer histogram + tiny contraction. Measured absmax 1.2e-4 vs 3.3e-4 tol.
//
// R2: two dispatches total; disjoint partial histograms, no global atomics.
// R3/R4: 1024-thread finalize kernel -> container failed twice, both rounds.
//        Only delta vs the passing R2 shape was the 1024-thread launch.
// R5: revert to 256-thread finalize (identical launch shape to R2), implement
//     the latency fix as memory-level parallelism instead:
//       phase 1: 4 q-slices interleaved in an unroll-8 partial loop
//                -> 32 loads in flight (4 latency rounds, was 16)
//       phase 2: unroll-32 contraction -> 32 table loads in flight
//                (8 latency rounds, was 64)

#define NQ      1024
#define NBINS   64
#define NIMG    24            // B*C = 8*3
#define IMG_PIX (512 * 512)   // 262144 pixels per (b,c) image
#define BPI     32            // count blocks per image
#define CNT_BLOCKS (NIMG * BPI)        // 768
#define TBL_BLOCKS (NQ / 4)            // 256 (4 quant cells per 256-thread block)

// ---- K1: fused count (blocks 0..767) + table build (blocks 768..1023) ----
__global__ __launch_bounds__(256) void soft_hist_k1(
    const float* __restrict__ x, const float* __restrict__ centers,
    float* __restrict__ table, unsigned int* __restrict__ parts)
{
    const int bid = blockIdx.x;
    const int t   = threadIdx.x;

    if (bid < CNT_BLOCKS) {
        // ---- per-(image,slice) histogram over NQ quant cells ----
        __shared__ unsigned int h[NQ];
        #pragma unroll
        for (int k = 0; k < NQ / 256; ++k) h[t + k * 256] = 0u;
        __syncthreads();

        // Block covers 2048 float4 (8192 pixels), contiguous 32 KB chunk.
        const float4* x4 = (const float4*)x + (size_t)bid * (IMG_PIX / 4 / BPI);

        // Prefetch all 8 float4 into registers -> 8 HBM loads in flight.
        float4 v[8];
        #pragma unroll
        for (int r = 0; r < 8; ++r) v[r] = x4[r * 256 + t];

        #pragma unroll
        for (int r = 0; r < 8; ++r) {
            const float4 p = v[r];
            int q0 = (int)(p.x * (float)NQ); q0 = q0 < 0 ? 0 : (q0 > NQ - 1 ? NQ - 1 : q0);
            int q1 = (int)(p.y * (float)NQ); q1 = q1 < 0 ? 0 : (q1 > NQ - 1 ? NQ - 1 : q1);
            int q2 = (int)(p.z * (float)NQ); q2 = q2 < 0 ? 0 : (q2 > NQ - 1 ? NQ - 1 : q2);
            int q3 = (int)(p.w * (float)NQ); q3 = q3 < 0 ? 0 : (q3 > NQ - 1 ? NQ - 1 : q3);
            atomicAdd(&h[q0], 1u);
            atomicAdd(&h[q1], 1u);
            atomicAdd(&h[q2], 1u);
            atomicAdd(&h[q3], 1u);
        }
        __syncthreads();

        // Plain coalesced store of this block's partial histogram (disjoint slot).
        unsigned int* dst = parts + (size_t)bid * NQ;
        #pragma unroll
        for (int k = 0; k < NQ / 256; ++k) dst[t + k * 256] = h[t + k * 256];
    } else {
        // ---- table[q][j] = normalized Gaussian kernel at quant-cell center q ----
        const int lane = t & 63;                       // bin (64 bins == 1 wave)
        const int q    = (bid - CNT_BLOCKS) * 4 + (t >> 6);
        const float cq = ((float)q + 0.5f) * (1.0f / (float)NQ);
        // (x - c)/(SIGMA + 1e-12); 0.02 + 1e-12 rounds to 0.02f in fp32
        const float d  = (cq - centers[lane]) * 50.0f;
        const float e  = expf(-0.5f * d * d);
        float s = e;
        #pragma unroll
        for (int off = 32; off > 0; off >>= 1) s += __shfl_xor(s, off, 64);
        table[q * NBINS + lane] = e / (s + 1e-12f);
    }
}

// ---- K2: sum partials; hist[j] = sum_q tot[q]*table[q][j]; /P; normalize ----
// 256 threads/block (same launch shape as the passing R2 kernel); latency is
// hidden with per-thread MLP instead of wider blocks.
__global__ __launch_bounds__(256) void soft_hist_final(
    const unsigned int* __restrict__ parts, const float* __restrict__ table,
    float* __restrict__ out)
{
    __shared__ float tf[NQ];
    __shared__ float part[4][NBINS];
    const int t   = threadIdx.x;
    const int img = blockIdx.x;

    // Phase 1: tf[q] = sum of this image's 32 partial histograms.
    // Thread t owns q in {t, t+256, t+512, t+768}; the 4 slices are
    // interleaved inside an unroll-8 loop over partials -> 32 independent
    // loads in flight per thread (4 latency rounds instead of 16).
    {
        const unsigned int* src = parts + (size_t)img * BPI * NQ + t;
        unsigned int s0 = 0, s1 = 0, s2 = 0, s3 = 0;
        #pragma unroll 8
        for (int b = 0; b < BPI; ++b) {
            const unsigned int* p = src + (size_t)b * NQ;
            s0 += p[0];
            s1 += p[256];
            s2 += p[512];
            s3 += p[768];
        }
        tf[t +   0] = (float)s0;
        tf[t + 256] = (float)s1;
        tf[t + 512] = (float)s2;
        tf[t + 768] = (float)s3;
    }
    __syncthreads();

    // Phase 2: group g (of 4) covers q in [g*256, g*256+256); lane j = bin.
    // Per iteration the wave reads 64 consecutive table floats (256B
    // coalesced); unroll-32 keeps 32 loads in flight (loads are independent
    // of the accumulate chain) -> 8 latency rounds instead of 64.
    const int j  = t & 63;     // bin
    const int g  = t >> 6;     // q-group
    const int Q4 = NQ / 4;
    float acc = 0.0f;
    const float* tb = table + (size_t)(g * Q4) * NBINS + j;
    #pragma unroll 32
    for (int qq = 0; qq < Q4; ++qq)
        acc += tb[(size_t)qq * NBINS] * tf[g * Q4 + qq];   // tf read is wave-broadcast
    part[g][j] = acc;
    __syncthreads();

    // Phase 3: reduce 4 group-partials, mean over pixels, per-image normalize.
    if (t < 64) {
        const float hsum = part[0][t] + part[1][t] + part[2][t] + part[3][t];
        const float hm   = hsum * (1.0f / (float)IMG_PIX);   // mean over pixels
        float ss = hm;
        #pragma unroll
        for (int off = 32; off > 0; off >>= 1) ss += __shfl_xor(ss, off, 64);
        out[img * NBINS + t] = hm / (ss + 1e-12f);           // per-image normalize
    }
}

extern "C" void kernel_launch(void* const* d_in, const int* in_sizes, int n_in,
                              void* d_out, int out_size, void* d_ws, size_t ws_size,
                              hipStream_t stream)
{
    const float* x       = (const float*)d_in[0];   // (8,3,512,512) fp32
    const float* centers = (const float*)d_in[1];   // (64,) fp32
    float* out           = (float*)d_out;           // (8,3,64) fp32

    float*        table = (float*)d_ws;                                    // 256 KB
    unsigned int* parts = (unsigned int*)((char*)d_ws
                        + (size_t)NQ * NBINS * sizeof(float));             // 3 MB

    soft_hist_k1<<<CNT_BLOCKS + TBL_BLOCKS, 256, 0, stream>>>(x, centers, table, parts);
    soft_hist_final<<<NIMG, 256, 0, stream>>>(parts, table, out);
}